// Round 1
// baseline (339.326 us; speedup 1.0000x reference)
//
#include <hip/hip_runtime.h>
#include <math.h>

// Shapes: B=64, T=256, R=49, H=1024
// out = [c_t (B*T*H = 16777216 fp32)] ++ [alpha (B*T*R = 802816 fp32)]

#define LDSS 68  // 64 + 4 pad: keeps b128 alignment (68*4=272 B, mult of 16) and spreads banks

// C[m][n] = sum_k A[m][k] * W[n][k];  K=1024, N=49 (padded to 64), M multiple of 64.
__global__ __launch_bounds__(256) void gemm_abt(const float* __restrict__ A,
                                                const float* __restrict__ W,
                                                float* __restrict__ C) {
    __shared__ float At[64 * LDSS];  // [k][m]
    __shared__ float Wt[64 * LDSS];  // [k][n]
    const int tid = threadIdx.x;
    const int tx = tid & 15;         // n-group
    const int ty = tid >> 4;         // m-group
    const int m0 = blockIdx.x * 64;

    float acc[4][4] = {};

    for (int kc = 0; kc < 1024; kc += 64) {
        // Load A tile: 64 m x 64 k = 1024 float4
#pragma unroll
        for (int p = 0; p < 4; ++p) {
            int f = tid + p * 256;
            int ml = f >> 4;
            int k4 = (f & 15) * 4;
            float4 v = *(const float4*)(A + (size_t)(m0 + ml) * 1024 + kc + k4);
            At[(k4 + 0) * LDSS + ml] = v.x;
            At[(k4 + 1) * LDSS + ml] = v.y;
            At[(k4 + 2) * LDSS + ml] = v.z;
            At[(k4 + 3) * LDSS + ml] = v.w;
        }
        // Load W tile: 64 n-slots x 64 k (n >= 49 zero-padded)
#pragma unroll
        for (int p = 0; p < 4; ++p) {
            int f = tid + p * 256;
            int nl = f >> 4;
            int k4 = (f & 15) * 4;
            float4 v = make_float4(0.f, 0.f, 0.f, 0.f);
            if (nl < 49) v = *(const float4*)(W + (size_t)nl * 1024 + kc + k4);
            Wt[(k4 + 0) * LDSS + nl] = v.x;
            Wt[(k4 + 1) * LDSS + nl] = v.y;
            Wt[(k4 + 2) * LDSS + nl] = v.z;
            Wt[(k4 + 3) * LDSS + nl] = v.w;
        }
        __syncthreads();
#pragma unroll
        for (int k = 0; k < 64; ++k) {
            float4 a = *(const float4*)(At + k * LDSS + ty * 4);
            float4 b = *(const float4*)(Wt + k * LDSS + tx * 4);
            acc[0][0] += a.x * b.x; acc[0][1] += a.x * b.y; acc[0][2] += a.x * b.z; acc[0][3] += a.x * b.w;
            acc[1][0] += a.y * b.x; acc[1][1] += a.y * b.y; acc[1][2] += a.y * b.z; acc[1][3] += a.y * b.w;
            acc[2][0] += a.z * b.x; acc[2][1] += a.z * b.y; acc[2][2] += a.z * b.z; acc[2][3] += a.z * b.w;
            acc[3][0] += a.w * b.x; acc[3][1] += a.w * b.y; acc[3][2] += a.w * b.z; acc[3][3] += a.w * b.w;
        }
        __syncthreads();
    }

#pragma unroll
    for (int i = 0; i < 4; ++i) {
        int m = m0 + ty * 4 + i;
#pragma unroll
        for (int j = 0; j < 4; ++j) {
            int n = tx * 4 + j;
            if (n < 49) C[(size_t)m * 49 + n] = acc[i][j];
        }
    }
}

// z[b,t,r] = sum_k tanh(cv[b,r,k] + cg[b,t,k]) * Wh[k]; alpha = softmax_r(z)
// One block handles (b, 16 consecutive t). grid = B * (T/16) = 1024.
__global__ __launch_bounds__(256) void zsoftmax(const float* __restrict__ cv,
                                                const float* __restrict__ cg,
                                                const float* __restrict__ Wh,
                                                float* __restrict__ alpha) {
    const int b = blockIdx.x >> 4;
    const int t0 = (blockIdx.x & 15) * 16;
    __shared__ float cvl[49 * 49];   // 2401
    __shared__ float cgl[16 * 49];   // 784
    __shared__ float whl[49];

    const int tid = threadIdx.x;
    for (int i = tid; i < 2401; i += 256) cvl[i] = cv[(size_t)b * 2401 + i];
    for (int i = tid; i < 16 * 49; i += 256) cgl[i] = cg[((size_t)b * 256 + t0) * 49 + i];
    if (tid < 49) whl[tid] = Wh[tid];
    __syncthreads();

    const int wave = tid >> 6;
    const int lane = tid & 63;

    for (int i = 0; i < 4; ++i) {
        const int tl = wave * 4 + i;  // 0..15
        float z = -INFINITY;
        if (lane < 49) {
            float s = 0.f;
            const float* cvr = cvl + lane * 49;  // stride 49: 2-way bank alias, free
            const float* cgr = cgl + tl * 49;    // wave-broadcast
            for (int k = 0; k < 49; ++k) {
                float x = cvr[k] + cgr[k];
                // tanh(x) = 1 - 2/(exp(2x)+1); stable at +-inf overflow
                float e = __expf(2.f * x);
                float th = 1.f - 2.f / (e + 1.f);
                s += th * whl[k];
            }
            z = s;
        }
        float m = z;
        for (int off = 32; off; off >>= 1) m = fmaxf(m, __shfl_xor(m, off));
        float p = (lane < 49) ? __expf(z - m) : 0.f;
        float sum = p;
        for (int off = 32; off; off >>= 1) sum += __shfl_xor(sum, off);
        if (lane < 49)
            alpha[(((size_t)b * 256) + t0 + tl) * 49 + lane] = p / sum;
    }
}

// c_t[b,t,h] = sum_{r<49} alpha[b,t,r] * V[b,r,h]
// Block tile: one b, 64 t, 64 h. grid = B * 4 * 16 = 4096.
__global__ __launch_bounds__(256) void ct_kernel(const float* __restrict__ alpha,
                                                 const float* __restrict__ V,
                                                 float* __restrict__ C) {
    const int id = blockIdx.x;
    const int b = id >> 6;
    const int t0 = ((id >> 4) & 3) * 64;
    const int h0 = (id & 15) * 64;

    __shared__ float al[49 * LDSS];  // [r][t], padded
    __shared__ float vl[49 * 64];    // [r][h]

    const int tid = threadIdx.x;
    for (int i = tid; i < 64 * 49; i += 256) {
        int t = i / 49;
        int r = i - t * 49;
        al[r * LDSS + t] = alpha[(((size_t)b * 256) + t0 + t) * 49 + r];
    }
    for (int i = tid; i < 49 * 64; i += 256) {
        int r = i >> 6;
        int h = i & 63;
        vl[i] = V[((size_t)b * 49 + r) * 1024 + h0 + h];
    }
    __syncthreads();

    const int tx = tid & 15;
    const int ty = tid >> 4;
    float acc[4][4] = {};

    for (int r = 0; r < 49; ++r) {
        float4 a = *(const float4*)(al + r * LDSS + ty * 4);
        float4 v = *(const float4*)(vl + r * 64 + tx * 4);
        acc[0][0] += a.x * v.x; acc[0][1] += a.x * v.y; acc[0][2] += a.x * v.z; acc[0][3] += a.x * v.w;
        acc[1][0] += a.y * v.x; acc[1][1] += a.y * v.y; acc[1][2] += a.y * v.z; acc[1][3] += a.y * v.w;
        acc[2][0] += a.z * v.x; acc[2][1] += a.z * v.y; acc[2][2] += a.z * v.z; acc[2][3] += a.z * v.w;
        acc[3][0] += a.w * v.x; acc[3][1] += a.w * v.y; acc[3][2] += a.w * v.z; acc[3][3] += a.w * v.w;
    }

#pragma unroll
    for (int i = 0; i < 4; ++i) {
        int t = t0 + ty * 4 + i;
        float4 o;
        o.x = acc[i][0]; o.y = acc[i][1]; o.z = acc[i][2]; o.w = acc[i][3];
        *(float4*)(C + (((size_t)b * 256) + t) * 1024 + h0 + tx * 4) = o;
    }
}

extern "C" void kernel_launch(void* const* d_in, const int* in_sizes, int n_in,
                              void* d_out, int out_size, void* d_ws, size_t ws_size,
                              hipStream_t stream) {
    const float* V   = (const float*)d_in[0];  // [64,49,1024]
    const float* h_t = (const float*)d_in[1];  // [64,256,1024]
    const float* Wv  = (const float*)d_in[2];  // [49,1024]
    const float* Wg  = (const float*)d_in[3];  // [49,1024]
    const float* Wh  = (const float*)d_in[4];  // [1,49]

    float* c_t   = (float*)d_out;                    // 16777216 floats
    float* alpha = (float*)d_out + 16777216;         // 802816 floats

    float* cv = (float*)d_ws;                        // [3136][49]  = 153664 floats
    float* cg = (float*)d_ws + 153664;               // [16384][49] = 802816 floats

    // cv = V . Wv^T   (M = B*R = 3136)
    gemm_abt<<<3136 / 64, 256, 0, stream>>>(V, Wv, cv);
    // cg = h_t . Wg^T (M = B*T = 16384)
    gemm_abt<<<16384 / 64, 256, 0, stream>>>(h_t, Wg, cg);
    // z -> softmax -> alpha
    zsoftmax<<<64 * 16, 256, 0, stream>>>(cv, cg, Wh, alpha);
    // c_t = alpha . V
    ct_kernel<<<64 * 4 * 16, 256, 0, stream>>>(alpha, V, c_t);
}

// Round 2
// 203.832 us; speedup vs baseline: 1.6647x; 1.6647x over previous
//
#include <hip/hip_runtime.h>
#include <math.h>
#include <stdint.h>

// Shapes: B=64, T=256, R=49, H=1024
// out = [c_t (B*T*H = 16777216 fp32)] ++ [alpha (B*T*R = 802816 fp32)]

typedef __attribute__((ext_vector_type(8))) short bf16x8;
typedef __attribute__((ext_vector_type(4))) float floatx4;

static __device__ __forceinline__ short f2bf(float f) {
    uint32_t u = __float_as_uint(f);
    u += 0x7FFF + ((u >> 16) & 1);  // RTNE
    return (short)(u >> 16);
}

static __device__ __forceinline__ bf16x8 pack8(float4 a, float4 b) {
    bf16x8 v;
    v[0] = f2bf(a.x); v[1] = f2bf(a.y); v[2] = f2bf(a.z); v[3] = f2bf(a.w);
    v[4] = f2bf(b.x); v[5] = f2bf(b.y); v[6] = f2bf(b.z); v[7] = f2bf(b.w);
    return v;
}

// C[m][n] = sum_k A[m][k]*W[n][k], K=1024, N=49 (padded 64), bf16 MFMA.
// M-tile 32, blocks 0..97 -> cv (V, Wv), 98..609 -> cg (h_t, Wg).
// LDS layout: row-major 64 bf16/row, 16B groups XOR-swizzled by (row&7).
__global__ __launch_bounds__(256) void gemm_mfma(const float* __restrict__ Av,
                                                 const float* __restrict__ Ag,
                                                 const float* __restrict__ Wv,
                                                 const float* __restrict__ Wg,
                                                 float* __restrict__ Cv,
                                                 float* __restrict__ Cg) {
    const int bid = blockIdx.x;
    const float* A; const float* W; float* C; int m0;
    if (bid < 98) { A = Av; W = Wv; C = Cv; m0 = bid * 32; }
    else          { A = Ag; W = Wg; C = Cg; m0 = (bid - 98) * 32; }

    __shared__ __align__(16) short As[32 * 64];
    __shared__ __align__(16) short Ws[64 * 64];

    const int tid = threadIdx.x;
    const int wave = tid >> 6, lane = tid & 63;
    const int quad = lane >> 4, l16 = lane & 15;
    const int mb = (wave & 1) * 16;   // wave's m offset in tile
    const int nb = (wave >> 1) * 32;  // wave's n offset in tile

    floatx4 acc[2] = {};

    // staging: A tile 32x64 (8 floats/thread), W tile 64x64 (16 floats/thread)
    const int arow = tid >> 3, ag = tid & 7;
    const int wrow = tid >> 2, wq = tid & 3;
    const float* aptr = A + (size_t)(m0 + arow) * 1024 + ag * 8;
    const bool wvalid = wrow < 49;
    const float* wptr = W + (size_t)wrow * 1024 + wq * 16;

    for (int kc = 0; kc < 1024; kc += 64) {
        float4 a0 = *(const float4*)(aptr + kc);
        float4 a1 = *(const float4*)(aptr + kc + 4);
        float4 w0, w1, w2, w3;
        if (wvalid) {
            w0 = *(const float4*)(wptr + kc);
            w1 = *(const float4*)(wptr + kc + 4);
            w2 = *(const float4*)(wptr + kc + 8);
            w3 = *(const float4*)(wptr + kc + 12);
        } else {
            w0 = w1 = w2 = w3 = make_float4(0.f, 0.f, 0.f, 0.f);
        }
        __syncthreads();  // prior compute done before overwrite
        *(bf16x8*)(As + arow * 64 + (ag ^ (arow & 7)) * 8) = pack8(a0, a1);
        *(bf16x8*)(Ws + wrow * 64 + ((wq * 2) ^ (wrow & 7)) * 8) = pack8(w0, w1);
        *(bf16x8*)(Ws + wrow * 64 + ((wq * 2 + 1) ^ (wrow & 7)) * 8) = pack8(w2, w3);
        __syncthreads();

#pragma unroll
        for (int s = 0; s < 2; ++s) {
            const int am = mb + l16;
            bf16x8 af = *(const bf16x8*)(As + am * 64 + (((s << 2) + quad) ^ (am & 7)) * 8);
#pragma unroll
            for (int nt = 0; nt < 2; ++nt) {
                const int wn = nb + nt * 16 + l16;
                bf16x8 bf = *(const bf16x8*)(Ws + wn * 64 + (((s << 2) + quad) ^ (wn & 7)) * 8);
                acc[nt] = __builtin_amdgcn_mfma_f32_16x16x32_bf16(af, bf, acc[nt], 0, 0, 0);
            }
        }
    }

    // D layout: col(n) = lane&15, row(m) = quad*4 + reg
#pragma unroll
    for (int nt = 0; nt < 2; ++nt) {
        const int n = nb + nt * 16 + l16;
        if (n < 49) {
#pragma unroll
            for (int r = 0; r < 4; ++r) {
                const int m = m0 + mb + quad * 4 + r;
                C[(size_t)m * 49 + n] = acc[nt][r];
            }
        }
    }
}

// z[b,t,r] = sum_k tanh(cv[b,r,k] + cg[b,t,k]) * Wh[k]; alpha = softmax_r(z)
// One block: (b, 16 t). grid = 1024. Rows padded to 52 for float4 LDS reads.
__global__ __launch_bounds__(256) void zsoftmax(const float* __restrict__ cv,
                                                const float* __restrict__ cg,
                                                const float* __restrict__ Wh,
                                                float* __restrict__ alpha) {
    const int b = blockIdx.x >> 4;
    const int t0 = (blockIdx.x & 15) * 16;
    __shared__ __align__(16) float cvl[49 * 52];
    __shared__ __align__(16) float cgl[16 * 52];
    __shared__ __align__(16) float whl[52];

    const int tid = threadIdx.x;
    for (int i = tid; i < 49 * 49; i += 256) {
        int r = i / 49, k = i - r * 49;
        cvl[r * 52 + k] = cv[(size_t)b * 2401 + i];
    }
    for (int i = tid; i < 16 * 49; i += 256) {
        int t = i / 49, k = i - t * 49;
        cgl[t * 52 + k] = cg[((size_t)b * 256 + t0) * 49 + i];
    }
    if (tid < 52) whl[tid] = (tid < 49) ? Wh[tid] : 0.f;
    __syncthreads();

    const int wave = tid >> 6;
    const int lane = tid & 63;
    const float4* cvr = (const float4*)(cvl + lane * 52);
    const float4* wh4 = (const float4*)whl;

    for (int i = 0; i < 4; ++i) {
        const int tl = wave * 4 + i;
        float z = -INFINITY;
        if (lane < 49) {
            const float4* cgr = (const float4*)(cgl + tl * 52);
            float s = 0.f;
#pragma unroll 4
            for (int kk = 0; kk < 12; ++kk) {
                float4 x = cvr[kk], g = cgr[kk], w = wh4[kk];
                float e0 = __expf(2.f * (x.x + g.x));
                float e1 = __expf(2.f * (x.y + g.y));
                float e2 = __expf(2.f * (x.z + g.z));
                float e3 = __expf(2.f * (x.w + g.w));
                s += (1.f - 2.f / (e0 + 1.f)) * w.x;
                s += (1.f - 2.f / (e1 + 1.f)) * w.y;
                s += (1.f - 2.f / (e2 + 1.f)) * w.z;
                s += (1.f - 2.f / (e3 + 1.f)) * w.w;
            }
            {   // tail k = 48
                float x = cvl[lane * 52 + 48] + cgl[tl * 52 + 48];
                float e = __expf(2.f * x);
                s += (1.f - 2.f / (e + 1.f)) * whl[48];
            }
            z = s;
        }
        float m = z;
        for (int off = 32; off; off >>= 1) m = fmaxf(m, __shfl_xor(m, off));
        float p = (lane < 49) ? __expf(z - m) : 0.f;
        float sum = p;
        for (int off = 32; off; off >>= 1) sum += __shfl_xor(sum, off);
        if (lane < 49)
            alpha[(((size_t)b * 256) + t0 + tl) * 49 + lane] = p / sum;
    }
}

// c_t[b,t,h] = sum_{r<49} alpha[b,t,r] * V[b,r,h]
// Block tile: one b, 64 t, 128 h; thread tile 4t x 8h. grid = 64*4*8 = 2048.
__global__ __launch_bounds__(256) void ct_kernel(const float* __restrict__ alpha,
                                                 const float* __restrict__ V,
                                                 float* __restrict__ C) {
    const int bid = blockIdx.x;
    const int b = bid >> 5;
    const int t0 = ((bid >> 3) & 3) * 64;
    const int h0 = (bid & 7) * 128;

    __shared__ __align__(16) float al[49 * 68];   // [r][t]
    __shared__ __align__(16) float vl[49 * 132];  // [r][h]

    const int tid = threadIdx.x;
    for (int i = tid; i < 64 * 49; i += 256) {
        int t = i / 49, r = i - t * 49;
        al[r * 68 + t] = alpha[(((size_t)b * 256) + t0 + t) * 49 + r];
    }
    for (int i = tid; i < 49 * 32; i += 256) {
        int r = i >> 5, hq = i & 31;
        *(float4*)(vl + r * 132 + hq * 4) =
            *(const float4*)(V + ((size_t)b * 49 + r) * 1024 + h0 + hq * 4);
    }
    __syncthreads();

    const int tx = tid & 15;   // h: 8 floats at tx*8
    const int ty = tid >> 4;   // t: 4 at ty*4
    float acc[4][8] = {};

    for (int r = 0; r < 49; ++r) {
        float4 a = *(const float4*)(al + r * 68 + ty * 4);
        float4 v0 = *(const float4*)(vl + r * 132 + tx * 8);
        float4 v1 = *(const float4*)(vl + r * 132 + tx * 8 + 4);
        const float av[4] = {a.x, a.y, a.z, a.w};
        const float vv[8] = {v0.x, v0.y, v0.z, v0.w, v1.x, v1.y, v1.z, v1.w};
#pragma unroll
        for (int i = 0; i < 4; ++i)
#pragma unroll
            for (int j = 0; j < 8; ++j)
                acc[i][j] += av[i] * vv[j];
    }

#pragma unroll
    for (int i = 0; i < 4; ++i) {
        const size_t row = (((size_t)b * 256) + t0 + ty * 4 + i) * 1024 + h0 + tx * 8;
        float4 o0, o1;
        o0.x = acc[i][0]; o0.y = acc[i][1]; o0.z = acc[i][2]; o0.w = acc[i][3];
        o1.x = acc[i][4]; o1.y = acc[i][5]; o1.z = acc[i][6]; o1.w = acc[i][7];
        *(float4*)(C + row) = o0;
        *(float4*)(C + row + 4) = o1;
    }
}

extern "C" void kernel_launch(void* const* d_in, const int* in_sizes, int n_in,
                              void* d_out, int out_size, void* d_ws, size_t ws_size,
                              hipStream_t stream) {
    const float* V   = (const float*)d_in[0];  // [64,49,1024]
    const float* h_t = (const float*)d_in[1];  // [64,256,1024]
    const float* Wv  = (const float*)d_in[2];  // [49,1024]
    const float* Wg  = (const float*)d_in[3];  // [49,1024]
    const float* Wh  = (const float*)d_in[4];  // [1,49]

    float* c_t   = (float*)d_out;             // 16777216 floats
    float* alpha = (float*)d_out + 16777216;  // 802816 floats

    float* cv = (float*)d_ws;                 // [3136][49]
    float* cg = (float*)d_ws + 153664;        // [16384][49]

    // cv (98 blocks) + cg (512 blocks) fused
    gemm_mfma<<<610, 256, 0, stream>>>(V, h_t, Wv, Wg, cv, cg);
    zsoftmax<<<1024, 256, 0, stream>>>(cv, cg, Wh, alpha);
    ct_kernel<<<2048, 256, 0, stream>>>(alpha, V, c_t);
}

// Round 3
// 174.960 us; speedup vs baseline: 1.9395x; 1.1650x over previous
//
#include <hip/hip_runtime.h>
#include <hip/hip_bf16.h>
#include <math.h>
#include <stdint.h>

// Shapes: B=64, T=256, R=49, H=1024
// out = [c_t (B*T*H fp32)] ++ [alpha (B*T*R fp32)]
// ws  = [cv fp32 3136x49][cg fp32 16384x49][alpha16 bf16 16384x64 swizzled]
//       [vT bf16 64x1024x64 swizzled]  (~14.3 MB)

typedef __attribute__((ext_vector_type(8))) short bf16x8;
typedef __attribute__((ext_vector_type(4))) float floatx4;

static __device__ __forceinline__ bf16x8 pack8(float4 a, float4 b) {
    union { __hip_bfloat162 h[4]; bf16x8 v; } u;
    u.h[0] = __float22bfloat162_rn(make_float2(a.x, a.y));
    u.h[1] = __float22bfloat162_rn(make_float2(a.z, a.w));
    u.h[2] = __float22bfloat162_rn(make_float2(b.x, b.y));
    u.h[3] = __float22bfloat162_rn(make_float2(b.z, b.w));
    return u.v;
}

static __device__ __forceinline__ unsigned short f2bf_bits(float f) {
    union { __hip_bfloat16 h; unsigned short u; } c;
    c.h = __float2bfloat16(f);
    return c.u;
}

// Blocks 0..97: cv = V.Wv^T (M-tile 32); 98..609: cg = h_t.Wg^T;
// 610..1121: transpose V -> vT[b][h][r(pad 64)] bf16, octet-swizzled rows.
__global__ __launch_bounds__(256) void gemm_mfma_tr(const float* __restrict__ Av,
                                                    const float* __restrict__ Ag,
                                                    const float* __restrict__ Wv,
                                                    const float* __restrict__ Wg,
                                                    float* __restrict__ Cv,
                                                    float* __restrict__ Cg,
                                                    unsigned short* __restrict__ vT) {
    __shared__ __align__(16) char smem[49 * 132 * 4];  // 25872 B, union
    const int bid = blockIdx.x;
    const int tid = threadIdx.x;

    if (bid >= 610) {
        // ---- V transpose: one (b, 128-h slice) per block ----
        float* Ts = (float*)smem;  // [49][132]
        const int tb = bid - 610;
        const int b = tb >> 3;
        const int h0 = (tb & 7) * 128;
        for (int i = tid; i < 49 * 32; i += 256) {
            const int r = i >> 5, hq = i & 31;
            *(float4*)(Ts + r * 132 + hq * 4) =
                *(const float4*)(Av + ((size_t)b * 49 + r) * 1024 + h0 + hq * 4);
        }
        __syncthreads();
        const int h = tid & 127;
        const int half = tid >> 7;  // 0: r 0..31 (octets 0..3), 1: r 32..63 (4..7)
        float f[32];
#pragma unroll
        for (int j = 0; j < 32; ++j) {
            const int r = half * 32 + j;
            f[j] = (r < 49) ? Ts[r * 132 + h] : 0.f;
        }
        const size_t rowbase = ((size_t)b * 1024 + h0 + h) * 64;
#pragma unroll
        for (int o2 = 0; o2 < 4; ++o2) {
            const int o = half * 4 + o2;
            bf16x8 v = pack8(make_float4(f[o2*8+0], f[o2*8+1], f[o2*8+2], f[o2*8+3]),
                             make_float4(f[o2*8+4], f[o2*8+5], f[o2*8+6], f[o2*8+7]));
            *(bf16x8*)(vT + rowbase + (size_t)((o ^ (h & 7)) * 8)) = v;
        }
        return;
    }

    // ---- GEMM C[m][n] = sum_k A[m][k]*W[n][k], K=1024, N=49->64 ----
    short* As = (short*)smem;           // [32][64]
    short* Ws = (short*)(smem + 4096);  // [64][64]
    const float* A; const float* W; float* C; int m0;
    if (bid < 98) { A = Av; W = Wv; C = Cv; m0 = bid * 32; }
    else          { A = Ag; W = Wg; C = Cg; m0 = (bid - 98) * 32; }

    const int wave = tid >> 6, lane = tid & 63;
    const int quad = lane >> 4, l16 = lane & 15;
    const int mb = (wave & 1) * 16;
    const int nb = (wave >> 1) * 32;

    floatx4 acc[2] = {};

    const int arow = tid >> 3, ag = tid & 7;
    const int wrow = tid >> 2, wq = tid & 3;
    const float* aptr = A + (size_t)(m0 + arow) * 1024 + ag * 8;
    const bool wvalid = wrow < 49;
    const float* wptr = W + (size_t)wrow * 1024 + wq * 16;

    float4 a0 = *(const float4*)(aptr);
    float4 a1 = *(const float4*)(aptr + 4);
    float4 w0 = make_float4(0.f,0.f,0.f,0.f), w1 = w0, w2 = w0, w3 = w0;
    if (wvalid) {
        w0 = *(const float4*)(wptr);
        w1 = *(const float4*)(wptr + 4);
        w2 = *(const float4*)(wptr + 8);
        w3 = *(const float4*)(wptr + 12);
    }

    for (int kc = 0; kc < 1024; kc += 64) {
        __syncthreads();
        *(bf16x8*)(As + arow * 64 + (ag ^ (arow & 7)) * 8) = pack8(a0, a1);
        *(bf16x8*)(Ws + wrow * 64 + ((wq * 2) ^ (wrow & 7)) * 8) = pack8(w0, w1);
        *(bf16x8*)(Ws + wrow * 64 + ((wq * 2 + 1) ^ (wrow & 7)) * 8) = pack8(w2, w3);
        __syncthreads();
        if (kc < 960) {  // prefetch next tile; latency hides under MFMA below
            a0 = *(const float4*)(aptr + kc + 64);
            a1 = *(const float4*)(aptr + kc + 68);
            if (wvalid) {
                w0 = *(const float4*)(wptr + kc + 64);
                w1 = *(const float4*)(wptr + kc + 68);
                w2 = *(const float4*)(wptr + kc + 72);
                w3 = *(const float4*)(wptr + kc + 76);
            }
        }
#pragma unroll
        for (int s = 0; s < 2; ++s) {
            const int am = mb + l16;
            bf16x8 af = *(const bf16x8*)(As + am * 64 + (((s << 2) + quad) ^ (am & 7)) * 8);
#pragma unroll
            for (int nt = 0; nt < 2; ++nt) {
                const int wn = nb + nt * 16 + l16;
                bf16x8 bf = *(const bf16x8*)(Ws + wn * 64 + (((s << 2) + quad) ^ (wn & 7)) * 8);
                acc[nt] = __builtin_amdgcn_mfma_f32_16x16x32_bf16(af, bf, acc[nt], 0, 0, 0);
            }
        }
    }

#pragma unroll
    for (int nt = 0; nt < 2; ++nt) {
        const int n = nb + nt * 16 + l16;
        if (n < 49) {
#pragma unroll
            for (int r = 0; r < 4; ++r) {
                const int m = m0 + mb + quad * 4 + r;
                C[(size_t)m * 49 + n] = acc[nt][r];
            }
        }
    }
}

// z[b,t,r] = sum_k tanh(cv[b,r,k]+cg[b,t,k])*Wh[k]; alpha = softmax_r(z).
// Writes fp32 alpha to d_out and bf16 swizzled padded alpha16 to ws.
__global__ __launch_bounds__(256) void zsoftmax(const float* __restrict__ cv,
                                                const float* __restrict__ cg,
                                                const float* __restrict__ Wh,
                                                float* __restrict__ alpha,
                                                unsigned short* __restrict__ a16) {
    const int b = blockIdx.x >> 4;
    const int t0 = (blockIdx.x & 15) * 16;
    __shared__ __align__(16) float cvl[49 * 52];
    __shared__ __align__(16) float cgl[16 * 52];
    __shared__ __align__(16) float whl[52];

    const int tid = threadIdx.x;
    for (int i = tid; i < 49 * 49; i += 256) {
        int r = i / 49, k = i - r * 49;
        cvl[r * 52 + k] = cv[(size_t)b * 2401 + i];
    }
    for (int i = tid; i < 16 * 49; i += 256) {
        int t = i / 49, k = i - t * 49;
        cgl[t * 52 + k] = cg[((size_t)b * 256 + t0) * 49 + i];
    }
    if (tid < 52) whl[tid] = (tid < 49) ? Wh[tid] : 0.f;
    __syncthreads();

    const int wave = tid >> 6;
    const int lane = tid & 63;
    const float4* cvr = (const float4*)(cvl + lane * 52);
    const float4* wh4 = (const float4*)whl;

    for (int i = 0; i < 4; ++i) {
        const int tl = wave * 4 + i;
        float z = -INFINITY;
        if (lane < 49) {
            const float4* cgr = (const float4*)(cgl + tl * 52);
            float s = 0.f;
#pragma unroll 4
            for (int kk = 0; kk < 12; ++kk) {
                float4 x = cvr[kk], g = cgr[kk], w = wh4[kk];
                float r0 = __builtin_amdgcn_rcpf(__expf(2.f * (x.x + g.x)) + 1.f);
                float r1 = __builtin_amdgcn_rcpf(__expf(2.f * (x.y + g.y)) + 1.f);
                float r2 = __builtin_amdgcn_rcpf(__expf(2.f * (x.z + g.z)) + 1.f);
                float r3 = __builtin_amdgcn_rcpf(__expf(2.f * (x.w + g.w)) + 1.f);
                s = fmaf(1.f - 2.f * r0, w.x, s);
                s = fmaf(1.f - 2.f * r1, w.y, s);
                s = fmaf(1.f - 2.f * r2, w.z, s);
                s = fmaf(1.f - 2.f * r3, w.w, s);
            }
            {
                float x = cvl[lane * 52 + 48] + cgl[tl * 52 + 48];
                float r0 = __builtin_amdgcn_rcpf(__expf(2.f * x) + 1.f);
                s = fmaf(1.f - 2.f * r0, whl[48], s);
            }
            z = s;
        }
        float m = z;
        for (int off = 32; off; off >>= 1) m = fmaxf(m, __shfl_xor(m, off));
        float p = (lane < 49) ? __expf(z - m) : 0.f;
        float sum = p;
        for (int off = 32; off; off >>= 1) sum += __shfl_xor(sum, off);
        const float val = p * __builtin_amdgcn_rcpf(sum);  // 0 for lane>=49

        const size_t grow = (size_t)b * 256 + t0 + tl;
        if (lane < 49) alpha[grow * 49 + lane] = val;
        // bf16 padded row, octet-swizzled for ct staging
        const int pos = (((lane >> 3) ^ (tl & 7)) << 3) | (lane & 7);
        a16[grow * 64 + pos] = f2bf_bits(val);
    }
}

// c_t[b,t,h] = sum_r alpha[b,t,r] * V[b,r,h] via bf16 MFMA (K=49 padded 64).
// Block: (b, 64 t, 128 h). Wave: 32t x 64h. grid = 64*4*8 = 2048.
__global__ __launch_bounds__(256) void ct_mfma(const unsigned short* __restrict__ a16,
                                               const unsigned short* __restrict__ vT,
                                               float* __restrict__ C) {
    const int bid = blockIdx.x;
    const int b = bid >> 5;
    const int t0 = ((bid >> 3) & 3) * 64;
    const int h0 = (bid & 7) * 128;

    __shared__ __align__(16) short Al[64 * 64];   // [t][r] bf16, swizzled
    __shared__ __align__(16) short Vl[128 * 64];  // [h][r] bf16, swizzled

    const int tid = threadIdx.x;
    {
        const bf16x8* src = (const bf16x8*)(a16 + ((size_t)b * 256 + t0) * 64);
        bf16x8* dst = (bf16x8*)Al;
#pragma unroll
        for (int p = 0; p < 2; ++p) dst[tid + p * 256] = src[tid + p * 256];
    }
    {
        const bf16x8* src = (const bf16x8*)(vT + ((size_t)b * 1024 + h0) * 64);
        bf16x8* dst = (bf16x8*)Vl;
#pragma unroll
        for (int p = 0; p < 4; ++p) dst[tid + p * 256] = src[tid + p * 256];
    }
    __syncthreads();

    const int wave = tid >> 6, lane = tid & 63;
    const int quad = lane >> 4, l16 = lane & 15;
    const int tb = (wave & 1) * 32;
    const int hb = (wave >> 1) * 64;

    floatx4 acc[2][4] = {};
#pragma unroll
    for (int kc = 0; kc < 2; ++kc) {
        bf16x8 af[2];
#pragma unroll
        for (int ms = 0; ms < 2; ++ms) {
            const int row = tb + ms * 16 + l16;
            af[ms] = *(const bf16x8*)(Al + row * 64 + (((kc << 2) + quad) ^ (row & 7)) * 8);
        }
#pragma unroll
        for (int ns = 0; ns < 4; ++ns) {
            const int row = hb + ns * 16 + l16;
            bf16x8 bf = *(const bf16x8*)(Vl + row * 64 + (((kc << 2) + quad) ^ (row & 7)) * 8);
#pragma unroll
            for (int ms = 0; ms < 2; ++ms)
                acc[ms][ns] = __builtin_amdgcn_mfma_f32_16x16x32_bf16(af[ms], bf, acc[ms][ns], 0, 0, 0);
        }
    }

#pragma unroll
    for (int ms = 0; ms < 2; ++ms) {
        const int t = t0 + tb + ms * 16 + quad * 4;
#pragma unroll
        for (int ns = 0; ns < 4; ++ns) {
            const int h = h0 + hb + ns * 16 + l16;
#pragma unroll
            for (int r = 0; r < 4; ++r)
                C[((size_t)b * 256 + t + r) * 1024 + h] = acc[ms][ns][r];
        }
    }
}

extern "C" void kernel_launch(void* const* d_in, const int* in_sizes, int n_in,
                              void* d_out, int out_size, void* d_ws, size_t ws_size,
                              hipStream_t stream) {
    const float* V   = (const float*)d_in[0];
    const float* h_t = (const float*)d_in[1];
    const float* Wv  = (const float*)d_in[2];
    const float* Wg  = (const float*)d_in[3];
    const float* Wh  = (const float*)d_in[4];

    float* c_t   = (float*)d_out;
    float* alpha = (float*)d_out + 16777216;

    float* cv = (float*)d_ws;                                        // 153664 f
    float* cg = cv + 153664;                                         // 802816 f
    unsigned short* a16 = (unsigned short*)((char*)d_ws + 3825920);  // 16384*64
    unsigned short* vT  = a16 + 16384 * 64;                          // 64*1024*64

    gemm_mfma_tr<<<610 + 512, 256, 0, stream>>>(V, h_t, Wv, Wg, cv, cg, vT);
    zsoftmax<<<1024, 256, 0, stream>>>(cv, cg, Wh, alpha, a16);
    ct_mfma<<<2048, 256, 0, stream>>>(a16, vT, c_t);
}